// Round 1
// baseline (538.073 us; speedup 1.0000x reference)
//
#include <hip/hip_runtime.h>
#include <math.h>

#define BB 64
#define NN 64
#define NM1 63
#define RR (NN*(NN-1))

// One block per (batch, receiver n>=1). 256 threads; thread t owns hidden
// column t of MLP1/MLP3. Algebraic fusion: agg = (sum_r relu(h_r)) @ W2 +
// cnt*b2 (aggregation is linear, W2 is post-relu) -> W2 applied once per
// object, not per relation (63x FLOP cut on MLP2).
__global__ __launch_bounds__(256) void gppp_kernel(
    const float* __restrict__ objects_state,  // (B,N,8)
    const float* __restrict__ objects_shape,  // (B,N,10)
    const float* __restrict__ relation_info,  // (B,R,3)
    const float* __restrict__ s_mean, const float* __restrict__ s_std,
    const float* __restrict__ sh_mean, const float* __restrict__ sh_std,
    const float* __restrict__ v_mean, const float* __restrict__ v_std,
    const float* __restrict__ W1, const float* __restrict__ b1,   // (32,256),(256)
    const float* __restrict__ W2, const float* __restrict__ b2,   // (256,128),(128)
    const float* __restrict__ W3, const float* __restrict__ b3,   // (141,256),(256)
    const float* __restrict__ W4, const float* __restrict__ b4,   // (256,3),(3)
    float* __restrict__ out)                  // (B,63,6)
{
    const int blk = blockIdx.x;
    const int b = blk / NM1;
    const int n = blk % NM1 + 1;     // n = 0 output row is dropped by the reference
    const int t = threadIdx.x;

    __shared__ float s_pos[NN*2];
    __shared__ float s_rstate[8];    // normalized receiver state
    __shared__ float s_rshape[10];   // normalized receiver shape
    __shared__ float s_hsum[256];
    __shared__ float s_part[256];
    __shared__ float s_q[141];
    __shared__ float s_h[256];
    __shared__ float s_out[3];

    // ---- Phase A: stage per-batch positions + receiver features ----
    if (t < NN*2) s_pos[t] = objects_state[(size_t)(b*NN + (t>>1))*8 + (t&1)];
    if (t < 8)  s_rstate[t] = (objects_state[(size_t)(b*NN+n)*8 + t] - s_mean[t]) / s_std[t];
    if (t >= 32 && t < 42) {
        int c = t - 32;
        s_rshape[c] = (objects_shape[(size_t)(b*NN+n)*10 + c] - sh_mean[c]) / sh_std[c];
    }
    __syncthreads();

    // hoist normalization constants into registers (uniform loads)
    float sm[8], ssd[8], shm[10], shs[10];
    #pragma unroll
    for (int c = 0; c < 8; ++c)  { sm[c] = s_mean[c];  ssd[c] = s_std[c]; }
    #pragma unroll
    for (int c = 0; c < 10; ++c) { shm[c] = sh_mean[c]; shs[c] = sh_std[c]; }

    const float px = s_pos[2*n], py = s_pos[2*n+1];
    const float rd0 = s_rstate[0], rd1 = s_rstate[1], rd2 = s_rstate[2],
                rd3 = s_rstate[3], rd4 = s_rstate[4], rd5 = s_rstate[5];

    float hsum = 0.f;
    int cnt = 0;

    // ---- Phase B: loop over this receiver's 63 candidate relations ----
    for (int k = 0; k < NM1; ++k) {
        const int j = k + (k >= n);
        float dx = px - s_pos[2*j];
        float dy = py - s_pos[2*j+1];
        float dist = sqrtf(dx*dx + dy*dy);
        if (!(dist < 0.35f && dist != 0.0f)) continue;  // block-uniform branch
        cnt++;

        // rel_data (32) in registers, identical in all threads (broadcast loads)
        float rel[32];
        const int r = n*NM1 + k;
        rel[0] = relation_info[((size_t)b*RR + r)*3 + 0];
        rel[1] = relation_info[((size_t)b*RR + r)*3 + 1];
        rel[2] = relation_info[((size_t)b*RR + r)*3 + 2];
        float sd[8];
        #pragma unroll
        for (int c = 0; c < 8; ++c)
            sd[c] = (objects_state[(size_t)(b*NN+j)*8 + c] - sm[c]) / ssd[c];
        const float d0 = sd[0]-rd0, d1 = sd[1]-rd1, d2 = sd[2]-rd2,
                    d3 = sd[3]-rd3, d4 = sd[4]-rd4, d5 = sd[5]-rd5;
        const float ca = cosf(rd2), sa = sinf(rd2);
        // basis rows [ca,sa],[-sa,ca]; temp cols (d0,d1),(d3,d4),(sd6,sd7)
        rel[3]  =  ca*d0 + sa*d1;
        rel[4]  = -sa*d0 + ca*d1;
        rel[5]  =  ca*d3 + sa*d4;
        rel[6]  = -sa*d3 + ca*d4;
        rel[7]  =  ca*sd[6] + sa*sd[7];
        rel[8]  = -sa*sd[6] + ca*sd[7];
        rel[9]  = sinf(2.f*d2);
        rel[10] = cosf(2.f*d2);
        rel[11] = d5;
        #pragma unroll
        for (int c = 0; c < 10; ++c) rel[12+c] = s_rshape[c];
        #pragma unroll
        for (int c = 0; c < 10; ++c)
            rel[22+c] = (objects_shape[(size_t)(b*NN+j)*10 + c] - shm[c]) / shs[c];

        // MLP1 column t: h = rel @ W1[:,t] + b1[t]; accumulate relu into hsum
        float h = b1[t];
        #pragma unroll
        for (int kk = 0; kk < 32; ++kk)
            h = fmaf(rel[kk], W1[kk*256 + t], h);
        hsum += fmaxf(h, 0.f);
    }

    s_hsum[t] = hsum;
    __syncthreads();

    // ---- Phase C: agg[e] = cnt*b2[e] + hsum @ W2[:,e] ----
    {
        const int e = t & 127, half = t >> 7;
        const int k0 = half * 128;
        float p = 0.f;
        for (int kk = 0; kk < 128; ++kk)
            p = fmaf(s_hsum[k0+kk], W2[(k0+kk)*128 + e], p);
        s_part[t] = p;
    }
    // obj_data into q[0..12]
    if (t < 13) {
        float v;
        if (t < 2) {
            const float ca = cosf(rd2), sa = sinf(rd2);
            v = (t == 0) ? ( ca*rd3 + sa*rd4)
                         : (-sa*rd3 + ca*rd4);
        } else if (t == 2) v = rd5;
        else v = s_rshape[t-3];
        s_q[t] = v;
    }
    __syncthreads();
    if (t < 128) s_q[13+t] = (float)cnt * b2[t] + s_part[t] + s_part[t+128];
    __syncthreads();

    // ---- MLP3: h2 = relu(q @ W3 + b3), column t ----
    float h2 = b3[t];
    for (int kk = 0; kk < 141; ++kk)
        h2 = fmaf(s_q[kk], W3[kk*256 + t], h2);
    h2 = fmaxf(h2, 0.f);
    s_h[t] = h2;
    __syncthreads();

    // out_vel[o] = h2 @ W4[:,o] + b4[o]
    if (t < 3) {
        float acc = b4[t];
        for (int kk = 0; kk < 256; ++kk)
            acc = fmaf(s_h[kk], W4[kk*3 + t], acc);
        s_out[t] = acc;
    }
    __syncthreads();

    // ---- epilogue: rotate back, compose x_next ----
    if (t < 6) {
        const float p0 = s_out[0]*v_std[0] + v_mean[0];
        const float p1 = s_out[1]*v_std[1] + v_mean[1];
        const float p2 = s_out[2]*v_std[2] + v_mean[2];
        const float ang = objects_state[(size_t)(b*NN+n)*8 + 2];  // raw angle
        const float ca = cosf(ang), sa = sinf(ang);
        const float xd0 = ca*p0 - sa*p1;
        const float xd1 = sa*p0 + ca*p1;
        const float xd[3] = { xd0, xd1, p2 };
        const float base = (t < 3) ? objects_state[(size_t)(b*NN+n)*8 + t] : 0.f;
        out[((size_t)b*NM1 + (n-1))*6 + t] = base + xd[t % 3];
    }
}

extern "C" void kernel_launch(void* const* d_in, const int* in_sizes, int n_in,
                              void* d_out, int out_size, void* d_ws, size_t ws_size,
                              hipStream_t stream) {
    gppp_kernel<<<dim3(BB*NM1), dim3(256), 0, stream>>>(
        (const float*)d_in[0],  (const float*)d_in[1],  (const float*)d_in[2],
        (const float*)d_in[3],  (const float*)d_in[4],  (const float*)d_in[5],
        (const float*)d_in[6],  (const float*)d_in[7],  (const float*)d_in[8],
        (const float*)d_in[9],  (const float*)d_in[10], (const float*)d_in[11],
        (const float*)d_in[12], (const float*)d_in[13], (const float*)d_in[14],
        (const float*)d_in[15], (const float*)d_in[16],
        (float*)d_out);
}

// Round 2
// 139.925 us; speedup vs baseline: 3.8454x; 3.8454x over previous
//
#include <hip/hip_runtime.h>
#include <math.h>

#define BB 64
#define NN 64
#define NM1 63
#define RR (NN*(NN-1))
#define RELW 24   // compact rel row stride: 22 used + 2 pad = 96 B (16B-aligned for float4)

// One block per (batch, receiver n>=1), 256 threads.
// Compact rel features (22): [0..2] relation_info, [3..11] geometric diff
// feats, [12..21] normalized SENDER shape. Receiver-shape terms (orig cols
// 12..21) are relation-invariant -> folded into hr_base once per block.
// agg = (sum_r relu(h_r)) @ W2 + cnt*b2  (W2 hoisted out of relation loop).
__global__ __launch_bounds__(256) void gppp_kernel(
    const float* __restrict__ objects_state,  // (B,N,8)
    const float* __restrict__ objects_shape,  // (B,N,10)
    const float* __restrict__ relation_info,  // (B,R,3)
    const float* __restrict__ s_mean, const float* __restrict__ s_std,
    const float* __restrict__ sh_mean, const float* __restrict__ sh_std,
    const float* __restrict__ v_mean, const float* __restrict__ v_std,
    const float* __restrict__ W1, const float* __restrict__ b1,   // (32,256)
    const float* __restrict__ W2, const float* __restrict__ b2,   // (256,128)
    const float* __restrict__ W3, const float* __restrict__ b3,   // (141,256)
    const float* __restrict__ W4, const float* __restrict__ b4,   // (256,3)
    float* __restrict__ out)                  // (B,63,6)
{
    const int blk = blockIdx.x;
    const int b = blk / NM1;
    const int n = blk % NM1 + 1;
    const int t = threadIdx.x;

    __shared__ __align__(16) float s_pos[NN*2];
    __shared__ float s_rstate[8];
    __shared__ float s_rshape[10];
    __shared__ __align__(16) float s_rel[NM1*RELW];
    __shared__ int   s_cnt;
    __shared__ __align__(16) float s_hsum[256];
    __shared__ float s_part[256];
    __shared__ __align__(16) float s_q[144];   // 141 used, padded
    __shared__ float s_red[4][3];
    __shared__ float s_out[3];

    // ---- Phase A: stage positions + receiver features ----
    if (t < NN*2) s_pos[t] = objects_state[(size_t)(b*NN + (t>>1))*8 + (t&1)];
    if (t < 8)  s_rstate[t] = (objects_state[(size_t)(b*NN+n)*8 + t] - s_mean[t]) / s_std[t];
    if (t >= 64 && t < 74) {           // wave 1 does receiver shape
        int c = t - 64;
        s_rshape[c] = (objects_shape[(size_t)(b*NN+n)*10 + c] - sh_mean[c]) / sh_std[c];
    }
    if (t == 128) s_cnt = 0;
    __syncthreads();

    // ---- All threads: hoist W1 compact column into registers (L1-resident)
    // (overlaps with wave 0's relation build below)
    float w1r[22];
    #pragma unroll
    for (int c = 0; c < 12; ++c) w1r[c] = W1[c*256 + t];
    #pragma unroll
    for (int c = 0; c < 10; ++c) w1r[12+c] = W1[(22+c)*256 + t];
    float hr_base = b1[t];
    #pragma unroll
    for (int c = 0; c < 10; ++c)
        hr_base = fmaf(s_rshape[c], W1[(12+c)*256 + t], hr_base);

    // ---- Wave 0: build compacted rel rows (one thread per candidate) ----
    if (t < NM1) {
        const int k = t;
        const int j = k + (k >= n);
        const float dx = s_pos[2*n]   - s_pos[2*j];
        const float dy = s_pos[2*n+1] - s_pos[2*j+1];
        const float dist = sqrtf(dx*dx + dy*dy);
        if (dist < 0.35f && dist != 0.0f) {
            const int slot = atomicAdd(&s_cnt, 1);
            float* rr = &s_rel[slot*RELW];
            const size_t rbase = ((size_t)b*RR + n*NM1 + k)*3;
            rr[0] = relation_info[rbase+0];
            rr[1] = relation_info[rbase+1];
            rr[2] = relation_info[rbase+2];
            float sd[8];
            #pragma unroll
            for (int c = 0; c < 8; ++c)
                sd[c] = (objects_state[(size_t)(b*NN+j)*8 + c] - s_mean[c]) / s_std[c];
            const float rd0 = s_rstate[0], rd1 = s_rstate[1], rd2 = s_rstate[2],
                        rd3 = s_rstate[3], rd4 = s_rstate[4], rd5 = s_rstate[5];
            const float d0 = sd[0]-rd0, d1 = sd[1]-rd1, d2 = sd[2]-rd2,
                        d3 = sd[3]-rd3, d4 = sd[4]-rd4, d5 = sd[5]-rd5;
            const float ca = cosf(rd2), sa = sinf(rd2);
            rr[3]  =  ca*d0 + sa*d1;
            rr[4]  = -sa*d0 + ca*d1;
            rr[5]  =  ca*d3 + sa*d4;
            rr[6]  = -sa*d3 + ca*d4;
            rr[7]  =  ca*sd[6] + sa*sd[7];
            rr[8]  = -sa*sd[6] + ca*sd[7];
            rr[9]  = sinf(2.f*d2);
            rr[10] = cosf(2.f*d2);
            rr[11] = d5;
            #pragma unroll
            for (int c = 0; c < 10; ++c)
                rr[12+c] = (objects_shape[(size_t)(b*NN+j)*10 + c] - sh_mean[c]) / sh_std[c];
        }
    }
    __syncthreads();
    const int cnt = s_cnt;

    // ---- MLP1 over active relations: float4 LDS broadcast + reg W1 ----
    float hsum = 0.f;
    for (int s = 0; s < cnt; ++s) {
        const float4* rp = (const float4*)&s_rel[s*RELW];
        const float4 x0 = rp[0], x1 = rp[1], x2 = rp[2], x3 = rp[3], x4 = rp[4];
        const float2 x5 = *(const float2*)&s_rel[s*RELW + 20];
        float h = hr_base;
        h = fmaf(x0.x, w1r[0],  h); h = fmaf(x0.y, w1r[1],  h);
        h = fmaf(x0.z, w1r[2],  h); h = fmaf(x0.w, w1r[3],  h);
        h = fmaf(x1.x, w1r[4],  h); h = fmaf(x1.y, w1r[5],  h);
        h = fmaf(x1.z, w1r[6],  h); h = fmaf(x1.w, w1r[7],  h);
        h = fmaf(x2.x, w1r[8],  h); h = fmaf(x2.y, w1r[9],  h);
        h = fmaf(x2.z, w1r[10], h); h = fmaf(x2.w, w1r[11], h);
        h = fmaf(x3.x, w1r[12], h); h = fmaf(x3.y, w1r[13], h);
        h = fmaf(x3.z, w1r[14], h); h = fmaf(x3.w, w1r[15], h);
        h = fmaf(x4.x, w1r[16], h); h = fmaf(x4.y, w1r[17], h);
        h = fmaf(x4.z, w1r[18], h); h = fmaf(x4.w, w1r[19], h);
        h = fmaf(x5.x, w1r[20], h); h = fmaf(x5.y, w1r[21], h);
        hsum += fmaxf(h, 0.f);
    }
    s_hsum[t] = hsum;
    __syncthreads();

    // ---- W2: agg[e] = cnt*b2[e] + hsum @ W2[:,e]  (split-K over 2 halves) --
    {
        const int e  = t & 127;
        const int k0 = (t >> 7) * 128;
        const float4* hp = (const float4*)&s_hsum[k0];
        float p = 0.f;
        for (int kk4 = 0; kk4 < 32; ++kk4) {
            const float4 hv = hp[kk4];
            const float* wrow = &W2[(size_t)(k0 + kk4*4)*128 + e];
            p = fmaf(hv.x, wrow[0],   p);
            p = fmaf(hv.y, wrow[128], p);
            p = fmaf(hv.z, wrow[256], p);
            p = fmaf(hv.w, wrow[384], p);
        }
        s_part[t] = p;
    }
    // obj_data -> q[0..12]
    if (t < 13) {
        const float rd2 = s_rstate[2], rd3 = s_rstate[3],
                    rd4 = s_rstate[4], rd5 = s_rstate[5];
        float v;
        if (t < 2) {
            const float ca = cosf(rd2), sa = sinf(rd2);
            v = (t == 0) ? ( ca*rd3 + sa*rd4) : (-sa*rd3 + ca*rd4);
        } else if (t == 2) v = rd5;
        else v = s_rshape[t-3];
        s_q[t] = v;
    }
    __syncthreads();
    if (t < 128) s_q[13+t] = (float)cnt * b2[t] + s_part[t] + s_part[t+128];
    __syncthreads();

    // ---- MLP3: h2[t] = relu(q @ W3[:,t] + b3[t]) ----
    float h2 = b3[t];
    {
        const float4* qp = (const float4*)s_q;
        for (int kk4 = 0; kk4 < 35; ++kk4) {
            const float4 qv = qp[kk4];
            const float* wrow = &W3[(size_t)(kk4*4)*256 + t];
            h2 = fmaf(qv.x, wrow[0],   h2);
            h2 = fmaf(qv.y, wrow[256], h2);
            h2 = fmaf(qv.z, wrow[512], h2);
            h2 = fmaf(qv.w, wrow[768], h2);
        }
        h2 = fmaf(s_q[140], W3[(size_t)140*256 + t], h2);
    }
    h2 = fmaxf(h2, 0.f);

    // ---- W4: all-thread partials + 64-lane shuffle reduce ----
    float p0 = h2 * W4[t*3 + 0];
    float p1 = h2 * W4[t*3 + 1];
    float p2 = h2 * W4[t*3 + 2];
    #pragma unroll
    for (int off = 32; off > 0; off >>= 1) {
        p0 += __shfl_down(p0, off);
        p1 += __shfl_down(p1, off);
        p2 += __shfl_down(p2, off);
    }
    if ((t & 63) == 0) {
        const int wv = t >> 6;
        s_red[wv][0] = p0; s_red[wv][1] = p1; s_red[wv][2] = p2;
    }
    __syncthreads();
    if (t < 3)
        s_out[t] = b4[t] + s_red[0][t] + s_red[1][t] + s_red[2][t] + s_red[3][t];
    __syncthreads();

    // ---- epilogue ----
    if (t < 6) {
        const float p0v = s_out[0]*v_std[0] + v_mean[0];
        const float p1v = s_out[1]*v_std[1] + v_mean[1];
        const float p2v = s_out[2]*v_std[2] + v_mean[2];
        const float ang = objects_state[(size_t)(b*NN+n)*8 + 2];
        const float ca = cosf(ang), sa = sinf(ang);
        const float xd[3] = { ca*p0v - sa*p1v, sa*p0v + ca*p1v, p2v };
        const float base = (t < 3) ? objects_state[(size_t)(b*NN+n)*8 + t] : 0.f;
        out[((size_t)b*NM1 + (n-1))*6 + t] = base + xd[t % 3];
    }
}

extern "C" void kernel_launch(void* const* d_in, const int* in_sizes, int n_in,
                              void* d_out, int out_size, void* d_ws, size_t ws_size,
                              hipStream_t stream) {
    gppp_kernel<<<dim3(BB*NM1), dim3(256), 0, stream>>>(
        (const float*)d_in[0],  (const float*)d_in[1],  (const float*)d_in[2],
        (const float*)d_in[3],  (const float*)d_in[4],  (const float*)d_in[5],
        (const float*)d_in[6],  (const float*)d_in[7],  (const float*)d_in[8],
        (const float*)d_in[9],  (const float*)d_in[10], (const float*)d_in[11],
        (const float*)d_in[12], (const float*)d_in[13], (const float*)d_in[14],
        (const float*)d_in[15], (const float*)d_in[16],
        (float*)d_out);
}

// Round 3
// 120.242 us; speedup vs baseline: 4.4749x; 1.1637x over previous
//
#include <hip/hip_runtime.h>
#include <math.h>

#define BB 64
#define NN 64
#define NM1 63
#define RR (NN*(NN-1))

typedef short bf16x8 __attribute__((ext_vector_type(8)));
typedef float f32x4 __attribute__((ext_vector_type(4)));

union U4 { uint4 u; bf16x8 b; };

__device__ inline unsigned int f2bf(float f) {
    unsigned int u = __float_as_uint(f);
    return (u + 0x7FFFu + ((u >> 16) & 1u)) >> 16;   // RNE fp32->bf16
}
__device__ inline unsigned int pack2(float a, float b) {
    return f2bf(a) | (f2bf(b) << 16);
}

// G=4 receivers per block, 256 threads, grid = 64 batches x 16 groups.
// MLP1 via bf16 MFMA 16x16x32 (M=relations, N=256 hidden, K=22 padded 32).
// agg = (sum relu(h)) @ W2 + cnt*b2 (W2 hoisted). W2/MLP3 fp32 VALU with
// split-K across the 4 waves to cut LDS broadcast reads.
// LDS (52.5 KB, aliased) -> 3 blocks/CU.
__global__ __launch_bounds__(256) void gppp_kernel(
    const float* __restrict__ objects_state,  // (B,N,8)
    const float* __restrict__ objects_shape,  // (B,N,10)
    const float* __restrict__ relation_info,  // (B,R,3)
    const float* __restrict__ s_mean, const float* __restrict__ s_std,
    const float* __restrict__ sh_mean, const float* __restrict__ sh_std,
    const float* __restrict__ v_mean, const float* __restrict__ v_std,
    const float* __restrict__ W1, const float* __restrict__ b1,   // (32,256)
    const float* __restrict__ W2, const float* __restrict__ b2,   // (256,128)
    const float* __restrict__ W3, const float* __restrict__ b3,   // (141,256)
    const float* __restrict__ W4, const float* __restrict__ b4,   // (256,3)
    float* __restrict__ out)                  // (B,63,6)
{
    __shared__ __align__(16) unsigned char smem[52480];
    // layout (bytes):
    float* s_posx = (float*)(smem);            // 64           @0
    float* s_posy = (float*)(smem+256);        // 64           @256
    float* s_rst  = (float*)(smem+512);        // [4][8]       @512
    float* s_rsh  = (float*)(smem+640);        // [4][12]      @640
    int*   s_cntg = (int*)(smem+832);          // [4]          @832
    float* s_outv = (float*)(smem+848);        // [4][4]       @848
    unsigned int* relb_w = (unsigned int*)(smem+1024);  // 256 rows x 20 words (80B)
    const uint4*  relb4  = (const uint4*)(smem+1024);   // row stride 5
    float* s_p3   = (float*)(smem+1024);       // [16][256] alias over relb (P5+)
    unsigned int* w1b_w = (unsigned int*)(smem+21504);  // 256 x 20 words
    const uint4*  w1b4  = (const uint4*)(smem+21504);
    float* s_p2   = (float*)(smem+21504);      // [16][128] alias over w1b (P3+)
    float* s_h    = (float*)(smem+29696);      // [4][256]  alias over w1b (P6+)
    float* s_base = (float*)(smem+41984);      // [4][256]
    float* s_hsum = (float*)(smem+46080);      // [4][256]
    const float4* s_hsum4 = (const float4*)(smem+46080);
    float* s_nsh  = (float*)(smem+46080);      // [64][11] alias over s_hsum (P0-P1)
    float* s_q    = (float*)(smem+50176);      // [4][144]
    const float4* s_q4 = (const float4*)(smem+50176);   // row stride 36
    float* s_nst  = (float*)(smem+50176);      // [64][9] alias over s_q (P0-P1)

    const int b  = blockIdx.x >> 4;
    const int bq = blockIdx.x & 15;
    const int nb = bq * 4;                     // receivers nb..nb+3 (n=0 skipped at store)
    const int t  = threadIdx.x;
    const int wv = t >> 6, lane = t & 63;
    const int col16 = lane & 15, quad = lane >> 4;

    // ================= Phase 0: stage =================
    if (t < 64) {
        s_posx[t] = objects_state[(size_t)(b*NN+t)*8 + 0];
        s_posy[t] = objects_state[(size_t)(b*NN+t)*8 + 1];
    }
    if (t >= 64 && t < 96) {
        int g = (t-64) >> 3, c = t & 7;
        s_rst[g*8+c] = (objects_state[(size_t)(b*NN+nb+g)*8 + c] - s_mean[c]) / s_std[c];
    }
    if (t >= 96 && t < 136) {
        int idx = t - 96; int g = idx/10, c = idx - g*10;
        s_rsh[g*12+c] = (objects_shape[(size_t)(b*NN+nb+g)*10 + c] - sh_mean[c]) / sh_std[c];
    }
    if (t >= 136 && t < 140) s_cntg[t-136] = 0;
    // all 64 normalized sender states / shapes
    #pragma unroll
    for (int i2 = 0; i2 < 2; ++i2) {
        int idx = t + i2*256;                  // 512 = 64*8
        int o = idx >> 3, c = idx & 7;
        s_nst[o*9+c] = (objects_state[(size_t)(b*NN+o)*8 + c] - s_mean[c]) / s_std[c];
    }
    #pragma unroll
    for (int i2 = 0; i2 < 3; ++i2) {
        int idx = t + i2*256;                  // 640 = 64*10
        if (idx < 640) {
            int o = idx/10, c = idx - o*10;
            s_nsh[o*11+c] = (objects_shape[(size_t)(b*NN+o)*10 + c] - sh_mean[c]) / sh_std[c];
        }
    }
    // W1 compact columns -> bf16 LDS (kc 0..11 <- rows 0..11, kc 12..21 <- rows 22..31)
    {
        float v[22];
        #pragma unroll
        for (int kc = 0; kc < 22; ++kc) {
            int orig = kc < 12 ? kc : kc + 10;
            v[kc] = W1[orig*256 + t];
        }
        #pragma unroll
        for (int w = 0; w < 11; ++w) w1b_w[t*20 + w] = pack2(v[2*w], v[2*w+1]);
        #pragma unroll
        for (int w = 11; w < 16; ++w) w1b_w[t*20 + w] = 0;
    }
    __syncthreads();

    // ================= Phase 1: s_base + relation build =================
    {
        float wvv[10];
        #pragma unroll
        for (int c = 0; c < 10; ++c) wvv[c] = W1[(12+c)*256 + t];
        const float bb = b1[t];
        #pragma unroll
        for (int g = 0; g < 4; ++g) {
            float acc = bb;
            #pragma unroll
            for (int c = 0; c < 10; ++c) acc = fmaf(s_rsh[g*12+c], wvv[c], acc);
            s_base[g*256+t] = acc;
        }
    }
    if (t < 252) {
        const int g = t/63, k = t - g*63;
        const int n = nb + g;
        const int j = k + (k >= n);
        const float dx = s_posx[n] - s_posx[j];
        const float dy = s_posy[n] - s_posy[j];
        const float dist = sqrtf(dx*dx + dy*dy);
        if (dist < 0.35f && dist != 0.0f) {
            const int slot = atomicAdd(&s_cntg[g], 1);
            const int row = g*64 + slot;
            float f[22];
            const size_t rb = ((size_t)b*RR + n*NM1 + k)*3;
            f[0] = relation_info[rb];
            f[1] = relation_info[rb+1];
            f[2] = relation_info[rb+2];
            float sd[8];
            #pragma unroll
            for (int c = 0; c < 8; ++c) sd[c] = s_nst[j*9+c];
            const float rd0 = s_rst[g*8+0], rd1 = s_rst[g*8+1], rd2 = s_rst[g*8+2],
                        rd3 = s_rst[g*8+3], rd4 = s_rst[g*8+4], rd5 = s_rst[g*8+5];
            const float d0 = sd[0]-rd0, d1 = sd[1]-rd1, d2 = sd[2]-rd2,
                        d3 = sd[3]-rd3, d4 = sd[4]-rd4, d5 = sd[5]-rd5;
            const float ca = cosf(rd2), sa = sinf(rd2);
            f[3]  =  ca*d0 + sa*d1;
            f[4]  = -sa*d0 + ca*d1;
            f[5]  =  ca*d3 + sa*d4;
            f[6]  = -sa*d3 + ca*d4;
            f[7]  =  ca*sd[6] + sa*sd[7];
            f[8]  = -sa*sd[6] + ca*sd[7];
            f[9]  = sinf(2.f*d2);
            f[10] = cosf(2.f*d2);
            f[11] = d5;
            #pragma unroll
            for (int c = 0; c < 10; ++c) f[12+c] = s_nsh[j*11+c];
            #pragma unroll
            for (int w = 0; w < 11; ++w) relb_w[row*20+w] = pack2(f[2*w], f[2*w+1]);
            #pragma unroll
            for (int w = 11; w < 16; ++w) relb_w[row*20+w] = 0;
        }
    }
    __syncthreads();

    // ================= Phase 2: MLP1 via MFMA =================
    {
        int cg[4];
        #pragma unroll
        for (int g = 0; g < 4; ++g) cg[g] = s_cntg[g];
        #pragma unroll
        for (int q4 = 0; q4 < 4; ++q4) {
            const int nt  = wv*4 + q4;
            const int col = nt*16 + col16;
            U4 bu; bu.u = w1b4[col*5 + quad];
            float hb[4], hs[4];
            #pragma unroll
            for (int g = 0; g < 4; ++g) { hb[g] = s_base[g*256+col]; hs[g] = 0.f; }
            #pragma unroll
            for (int g = 0; g < 4; ++g) {
                const int mts = (cg[g] + 15) >> 4;
                for (int mt = 0; mt < mts; ++mt) {
                    const int row = g*64 + mt*16 + col16;
                    U4 au; au.u = relb4[row*5 + quad];
                    f32x4 acc = {0.f, 0.f, 0.f, 0.f};
                    acc = __builtin_amdgcn_mfma_f32_16x16x32_bf16(au.b, bu.b, acc, 0, 0, 0);
                    const int rb2 = mt*16 + quad*4;
                    #pragma unroll
                    for (int i2 = 0; i2 < 4; ++i2) {
                        const float vv = fmaxf(acc[i2] + hb[g], 0.f);
                        hs[g] += (rb2 + i2 < cg[g]) ? vv : 0.f;
                    }
                }
            }
            #pragma unroll
            for (int g = 0; g < 4; ++g) {
                float vv = hs[g];
                vv += __shfl_xor(vv, 16);
                vv += __shfl_xor(vv, 32);
                if (quad == 0) s_hsum[g*256 + col] = vv;
            }
        }
    }
    __syncthreads();

    // ================= Phase 3: W2 partials (split-K by wave) + q[0..12] ====
    {
        const int k0 = wv * 64;
        float a0[4], a1[4];
        #pragma unroll
        for (int g = 0; g < 4; ++g) { a0[g] = 0.f; a1[g] = 0.f; }
        for (int k4 = 0; k4 < 16; ++k4) {
            float hv[4][4];
            #pragma unroll
            for (int g = 0; g < 4; ++g) {
                const float4 x = s_hsum4[g*64 + (k0 >> 2) + k4];
                hv[g][0] = x.x; hv[g][1] = x.y; hv[g][2] = x.z; hv[g][3] = x.w;
            }
            #pragma unroll
            for (int i2 = 0; i2 < 4; ++i2) {
                const int k = k0 + k4*4 + i2;
                const float wa = W2[(size_t)k*128 + lane];
                const float wb = W2[(size_t)k*128 + 64 + lane];
                #pragma unroll
                for (int g = 0; g < 4; ++g) {
                    a0[g] = fmaf(hv[g][i2], wa, a0[g]);
                    a1[g] = fmaf(hv[g][i2], wb, a1[g]);
                }
            }
        }
        #pragma unroll
        for (int g = 0; g < 4; ++g) {
            s_p2[(wv*4+g)*128 + lane]      = a0[g];
            s_p2[(wv*4+g)*128 + 64 + lane] = a1[g];
        }
    }
    if (t < 52) {
        const int g = t/13, c = t - g*13;
        const float rd2 = s_rst[g*8+2], rd3 = s_rst[g*8+3],
                    rd4 = s_rst[g*8+4], rd5 = s_rst[g*8+5];
        float v;
        if (c < 2) {
            const float ca = cosf(rd2), sa = sinf(rd2);
            v = (c == 0) ? (ca*rd3 + sa*rd4) : (-sa*rd3 + ca*rd4);
        } else if (c == 2) v = rd5;
        else v = s_rsh[g*12 + (c-3)];
        s_q[g*144 + c] = v;
    }
    __syncthreads();

    // ================= Phase 4: combine W2 partials -> q[13..140] ==========
    #pragma unroll
    for (int i2 = 0; i2 < 2; ++i2) {
        const int o = t + i2*256;
        const int g = o >> 7, e = o & 127;
        float acc = (float)s_cntg[g] * b2[e];
        #pragma unroll
        for (int w = 0; w < 4; ++w) acc += s_p2[(w*4+g)*128 + e];
        s_q[g*144 + 13 + e] = acc;
    }
    __syncthreads();

    // ================= Phase 5: MLP3 partials (split-K by wave) ============
    {
        const int kstart = wv * 36;
        const int nch = (wv == 3) ? 8 : 9;
        float acc[4][4];
        #pragma unroll
        for (int g = 0; g < 4; ++g)
            #pragma unroll
            for (int cr = 0; cr < 4; ++cr) acc[g][cr] = 0.f;
        for (int cch = 0; cch < nch; ++cch) {
            float qv[4][4];
            #pragma unroll
            for (int g = 0; g < 4; ++g) {
                const float4 x = s_q4[g*36 + (kstart >> 2) + cch];
                qv[g][0] = x.x; qv[g][1] = x.y; qv[g][2] = x.z; qv[g][3] = x.w;
            }
            #pragma unroll
            for (int i2 = 0; i2 < 4; ++i2) {
                const int k = kstart + cch*4 + i2;
                float w3v[4];
                #pragma unroll
                for (int cr = 0; cr < 4; ++cr) w3v[cr] = W3[(size_t)k*256 + lane + cr*64];
                #pragma unroll
                for (int g = 0; g < 4; ++g)
                    #pragma unroll
                    for (int cr = 0; cr < 4; ++cr)
                        acc[g][cr] = fmaf(qv[g][i2], w3v[cr], acc[g][cr]);
            }
        }
        if (wv == 3) {  // tail k = 140
            float w3v[4];
            #pragma unroll
            for (int cr = 0; cr < 4; ++cr) w3v[cr] = W3[(size_t)140*256 + lane + cr*64];
            #pragma unroll
            for (int g = 0; g < 4; ++g) {
                const float qs = s_q[g*144 + 140];
                #pragma unroll
                for (int cr = 0; cr < 4; ++cr) acc[g][cr] = fmaf(qs, w3v[cr], acc[g][cr]);
            }
        }
        #pragma unroll
        for (int g = 0; g < 4; ++g)
            #pragma unroll
            for (int cr = 0; cr < 4; ++cr)
                s_p3[(wv*4+g)*256 + lane + cr*64] = acc[g][cr];
    }
    __syncthreads();

    // ================= Phase 6: combine + relu -> s_h ======================
    {
        const float b3v = b3[t];
        #pragma unroll
        for (int g = 0; g < 4; ++g) {
            float acc = b3v;
            #pragma unroll
            for (int w = 0; w < 4; ++w) acc += s_p3[(w*4+g)*256 + t];
            s_h[g*256 + t] = fmaxf(acc, 0.f);
        }
    }
    __syncthreads();

    // ================= Phase 7: W4 (wave w owns g=w) =======================
    {
        float p0 = 0.f, p1 = 0.f, p2 = 0.f;
        #pragma unroll
        for (int cr = 0; cr < 4; ++cr) {
            const int col = lane + cr*64;
            const float h = s_h[wv*256 + col];
            p0 = fmaf(h, W4[col*3+0], p0);
            p1 = fmaf(h, W4[col*3+1], p1);
            p2 = fmaf(h, W4[col*3+2], p2);
        }
        #pragma unroll
        for (int off = 32; off > 0; off >>= 1) {
            p0 += __shfl_down(p0, off);
            p1 += __shfl_down(p1, off);
            p2 += __shfl_down(p2, off);
        }
        if (lane == 0) {
            s_outv[wv*4+0] = p0 + b4[0];
            s_outv[wv*4+1] = p1 + b4[1];
            s_outv[wv*4+2] = p2 + b4[2];
        }
    }
    __syncthreads();

    // ================= Phase 8: epilogue ===================================
    if (t < 24) {
        const int g = t/6, i = t - g*6;
        const int n = nb + g;
        if (n >= 1) {
            const float q0 = s_outv[g*4+0]*v_std[0] + v_mean[0];
            const float q1 = s_outv[g*4+1]*v_std[1] + v_mean[1];
            const float q2 = s_outv[g*4+2]*v_std[2] + v_mean[2];
            const float ang = objects_state[(size_t)(b*NN+n)*8 + 2];
            const float ca = cosf(ang), sa = sinf(ang);
            const float xd0 = ca*q0 - sa*q1;
            const float xd1 = sa*q0 + ca*q1;
            const int im = i % 3;
            const float xd = (im == 0) ? xd0 : (im == 1) ? xd1 : q2;
            const float base = (i < 3) ? objects_state[(size_t)(b*NN+n)*8 + i] : 0.f;
            out[((size_t)b*NM1 + (n-1))*6 + i] = base + xd;
        }
    }
}

extern "C" void kernel_launch(void* const* d_in, const int* in_sizes, int n_in,
                              void* d_out, int out_size, void* d_ws, size_t ws_size,
                              hipStream_t stream) {
    gppp_kernel<<<dim3(BB*16), dim3(256), 0, stream>>>(
        (const float*)d_in[0],  (const float*)d_in[1],  (const float*)d_in[2],
        (const float*)d_in[3],  (const float*)d_in[4],  (const float*)d_in[5],
        (const float*)d_in[6],  (const float*)d_in[7],  (const float*)d_in[8],
        (const float*)d_in[9],  (const float*)d_in[10], (const float*)d_in[11],
        (const float*)d_in[12], (const float*)d_in[13], (const float*)d_in[14],
        (const float*)d_in[15], (const float*)d_in[16],
        (float*)d_out);
}

// Round 4
// 109.603 us; speedup vs baseline: 4.9093x; 1.0971x over previous
//
#include <hip/hip_runtime.h>
#include <math.h>

#define BB 64
#define NN 64
#define NM1 63
#define RR (NN*(NN-1))

// workspace layout (bytes)
#define WS1_OFF 0              // W1c B-frags: 16 tiles * 64 lanes * 16B = 16 KB
#define WS2_OFF 16384          // W2 B-frags: 8 nt * 8 kc * 64 * 16B = 64 KB
#define WS3_OFF 81920          // W3 B-frags: 16 nt * 5 kc * 64 * 16B = 80 KB
#define WSH_OFF 163840         // hsum bf16: 4096 objs * 256 * 2B = 2 MB
#define WSC_OFF 2260992        // cnt int[4096]

typedef short bf16x8 __attribute__((ext_vector_type(8)));
typedef float f32x4 __attribute__((ext_vector_type(4)));
union U4 { uint4 u; bf16x8 b; };

__device__ inline unsigned int f2bf(float f) {
    unsigned int u = __float_as_uint(f);
    return (u + 0x7FFFu + ((u >> 16) & 1u)) >> 16;   // RNE fp32->bf16
}
__device__ inline unsigned int pack2(float a, float b) {
    return f2bf(a) | (f2bf(b) << 16);
}

// ============ K0: pack weights into bf16 MFMA B-fragment layout ============
// B-frag (16x16x32): lane l holds B[k=(l>>4)*8+j][n=nt*16+(l&15)], stored so
// lane l of tile (nt,kc) loads uint4 at index (tile*64+l) -> fully coalesced.
__global__ __launch_bounds__(64) void pack_kernel(
    const float* __restrict__ W1, const float* __restrict__ W2,
    const float* __restrict__ W3, unsigned char* __restrict__ ws)
{
    const int u = blockIdx.x, l = threadIdx.x;
    const int col16 = l & 15, quad = l >> 4;
    float v[8];
    uint4* dst;
    if (u < 16) {
        // W1 compact rows: kc<12 -> orig kc; 12..21 -> orig kc+10 (sender
        // shape rows 22..31); 22..31 -> orig kc-10 (receiver shape rows 12..21)
        const int nt = u, col = nt*16 + col16;
        #pragma unroll
        for (int j = 0; j < 8; ++j) {
            const int k = quad*8 + j;
            const int orig = k < 12 ? k : (k < 22 ? k+10 : k-10);
            v[j] = W1[orig*256 + col];
        }
        dst = (uint4*)(ws + WS1_OFF) + (nt*64 + l);
    } else if (u < 80) {
        const int w = u-16, nt = w >> 3, kc = w & 7, col = nt*16 + col16;
        #pragma unroll
        for (int j = 0; j < 8; ++j) {
            const int k = kc*32 + quad*8 + j;
            v[j] = W2[(size_t)k*128 + col];
        }
        dst = (uint4*)(ws + WS2_OFF) + ((nt*8 + kc)*64 + l);
    } else {
        const int w = u-80, nt = w/5, kc = w - nt*5, col = nt*16 + col16;
        #pragma unroll
        for (int j = 0; j < 8; ++j) {
            const int k = kc*32 + quad*8 + j;
            v[j] = (k < 141) ? W3[(size_t)k*256 + col] : 0.f;
        }
        dst = (uint4*)(ws + WS3_OFF) + ((nt*5 + kc)*64 + l);
    }
    uint4 o;
    o.x = pack2(v[0], v[1]); o.y = pack2(v[2], v[3]);
    o.z = pack2(v[4], v[5]); o.w = pack2(v[6], v[7]);
    *dst = o;
}

// ============ K1: relation build + MLP1 MFMA + hsum -> ws ============
// G=4 receivers/block, grid B*16. rel row = 32 bf16 exactly (22 feats +
// 10 receiver-shape) so no separate base term; K=32 = one MFMA K-step.
// LDS ~30.5 KB -> 5 blocks/CU.
__global__ __launch_bounds__(256) void rel_kernel(
    const float* __restrict__ objects_state,
    const float* __restrict__ objects_shape,
    const float* __restrict__ relation_info,
    const float* __restrict__ s_mean, const float* __restrict__ s_std,
    const float* __restrict__ sh_mean, const float* __restrict__ sh_std,
    const float* __restrict__ b1,
    unsigned char* __restrict__ ws)
{
    __shared__ float s_posx[64], s_posy[64];
    __shared__ float s_rst[4][8];
    __shared__ float s_rsh[4][12];
    __shared__ int   s_cntg[4];
    __shared__ float s_nst[64][9];
    __shared__ float s_nsh[64][11];
    __shared__ __align__(16) unsigned int relb_w[256*20];  // 64 rows/g, 80B stride (2-way banks)
    __shared__ float s_hsum[4][256];

    const int b  = blockIdx.x >> 4;
    const int nb = (blockIdx.x & 15) * 4;
    const int t  = threadIdx.x;
    const int wv = t >> 6, lane = t & 63, col16 = lane & 15, quad = lane >> 4;

    // ---- stage ----
    if (t < 64) {
        s_posx[t] = objects_state[(size_t)(b*NN+t)*8 + 0];
        s_posy[t] = objects_state[(size_t)(b*NN+t)*8 + 1];
    }
    if (t >= 64 && t < 96) {
        int g = (t-64) >> 3, c = t & 7;
        s_rst[g][c] = (objects_state[(size_t)(b*NN+nb+g)*8 + c] - s_mean[c]) / s_std[c];
    }
    if (t >= 96 && t < 136) {
        int idx = t-96, g = idx/10, c = idx - g*10;
        s_rsh[g][c] = (objects_shape[(size_t)(b*NN+nb+g)*10 + c] - sh_mean[c]) / sh_std[c];
    }
    if (t >= 136 && t < 140) s_cntg[t-136] = 0;
    #pragma unroll
    for (int r = 0; r < 2; ++r) {
        int idx = t + r*256, o = idx >> 3, c = idx & 7;
        s_nst[o][c] = (objects_state[(size_t)(b*NN+o)*8 + c] - s_mean[c]) / s_std[c];
    }
    #pragma unroll
    for (int r = 0; r < 3; ++r) {
        int idx = t + r*256;
        if (idx < 640) {
            int o = idx/10, c = idx - o*10;
            s_nsh[o][c] = (objects_shape[(size_t)(b*NN+o)*10 + c] - sh_mean[c]) / sh_std[c];
        }
    }
    __syncthreads();

    // ---- build compacted relation rows (bf16, 32 feats) ----
    if (t < 252) {
        const int g = t/63, k = t - g*63, n = nb + g, j = k + (k >= n);
        const float dx = s_posx[n] - s_posx[j];
        const float dy = s_posy[n] - s_posy[j];
        const float dist = sqrtf(dx*dx + dy*dy);
        if (dist < 0.35f && dist != 0.0f) {
            const int slot = atomicAdd(&s_cntg[g], 1);
            const int row = g*64 + slot;
            float f[32];
            const size_t rb = ((size_t)b*RR + n*NM1 + k)*3;
            f[0] = relation_info[rb];
            f[1] = relation_info[rb+1];
            f[2] = relation_info[rb+2];
            float sd[8];
            #pragma unroll
            for (int c = 0; c < 8; ++c) sd[c] = s_nst[j][c];
            const float rd0 = s_rst[g][0], rd1 = s_rst[g][1], rd2 = s_rst[g][2],
                        rd3 = s_rst[g][3], rd4 = s_rst[g][4], rd5 = s_rst[g][5];
            const float d0 = sd[0]-rd0, d1 = sd[1]-rd1, d2 = sd[2]-rd2,
                        d3 = sd[3]-rd3, d4 = sd[4]-rd4, d5 = sd[5]-rd5;
            const float ca = cosf(rd2), sa = sinf(rd2);
            f[3]  =  ca*d0 + sa*d1;
            f[4]  = -sa*d0 + ca*d1;
            f[5]  =  ca*d3 + sa*d4;
            f[6]  = -sa*d3 + ca*d4;
            f[7]  =  ca*sd[6] + sa*sd[7];
            f[8]  = -sa*sd[6] + ca*sd[7];
            f[9]  = sinf(2.f*d2);
            f[10] = cosf(2.f*d2);
            f[11] = d5;
            #pragma unroll
            for (int c = 0; c < 10; ++c) f[12+c] = s_nsh[j][c];   // sender shape
            #pragma unroll
            for (int c = 0; c < 10; ++c) f[22+c] = s_rsh[g][c];   // receiver shape
            uint4* dst = (uint4*)&relb_w[row*20];
            #pragma unroll
            for (int w4 = 0; w4 < 4; ++w4) {
                uint4 o;
                o.x = pack2(f[w4*8+0], f[w4*8+1]);
                o.y = pack2(f[w4*8+2], f[w4*8+3]);
                o.z = pack2(f[w4*8+4], f[w4*8+5]);
                o.w = pack2(f[w4*8+6], f[w4*8+7]);
                dst[w4] = o;
            }
        }
    }
    __syncthreads();

    // ---- MLP1 MFMA: per wave 4 N-tiles; B-frags coalesced from ws ----
    {
        int cg[4];
        #pragma unroll
        for (int g = 0; g < 4; ++g) cg[g] = s_cntg[g];
        const uint4* w1f = (const uint4*)(ws + WS1_OFF);
        #pragma unroll
        for (int q4 = 0; q4 < 4; ++q4) {
            const int nt = wv*4 + q4, col = nt*16 + col16;
            U4 bu; bu.u = w1f[nt*64 + lane];
            const float b1v = b1[col];
            float hs[4] = {0.f, 0.f, 0.f, 0.f};
            #pragma unroll
            for (int g = 0; g < 4; ++g) {
                const int mts = (cg[g] + 15) >> 4;
                for (int mt = 0; mt < mts; ++mt) {
                    U4 au; au.u = *(const uint4*)&relb_w[(g*64 + mt*16 + col16)*20 + quad*4];
                    f32x4 acc = {0.f, 0.f, 0.f, 0.f};
                    acc = __builtin_amdgcn_mfma_f32_16x16x32_bf16(au.b, bu.b, acc, 0, 0, 0);
                    const int rb2 = mt*16 + quad*4;
                    #pragma unroll
                    for (int i = 0; i < 4; ++i) {
                        const float vv = fmaxf(acc[i] + b1v, 0.f);
                        hs[g] += (rb2 + i < cg[g]) ? vv : 0.f;
                    }
                }
            }
            #pragma unroll
            for (int g = 0; g < 4; ++g) {
                float vv = hs[g];
                vv += __shfl_xor(vv, 16);
                vv += __shfl_xor(vv, 32);
                if (quad == 0) s_hsum[g][col] = vv;
            }
        }
    }
    __syncthreads();

    // ---- store hsum (bf16) + cnt ----
    {
        unsigned int* hdst = (unsigned int*)(ws + WSH_OFF);
        #pragma unroll
        for (int r = 0; r < 2; ++r) {
            const int idx = r*256 + t, g = idx >> 7, i = idx & 127;
            const int obj = b*NN + nb + g;
            hdst[obj*128 + i] = pack2(s_hsum[g][2*i], s_hsum[g][2*i+1]);
        }
        if (t < 4) ((int*)(ws + WSC_OFF))[b*NN + nb + t] = s_cntg[t];
    }
}

// ============ K2: per-object chain W2 -> W3 -> W4 -> epilogue ============
// M=16 objects/block, grid B*4. W2/W3 as MFMA GEMMs, A-side bf16.
__global__ __launch_bounds__(256) void obj_kernel(
    const float* __restrict__ objects_state,
    const float* __restrict__ objects_shape,
    const float* __restrict__ s_mean, const float* __restrict__ s_std,
    const float* __restrict__ sh_mean, const float* __restrict__ sh_std,
    const float* __restrict__ v_mean, const float* __restrict__ v_std,
    const float* __restrict__ b2, const float* __restrict__ b3,
    const float* __restrict__ W4, const float* __restrict__ b4,
    const unsigned char* __restrict__ ws,
    float* __restrict__ out)
{
    __shared__ __align__(16) unsigned short s_q[16*168];  // q rows, stride 168 u16 (84 words: 2-way banks)
    __shared__ float s_red[4][16][3];
    __shared__ float s_outv[16][3];

    const int bi = blockIdx.x >> 2, ot = blockIdx.x & 3;
    const int obj0 = bi*NN + ot*16;
    const int t = threadIdx.x, wv = t >> 6, lane = t & 63,
              col16 = lane & 15, quad = lane >> 4;

    // zero K-pad cols 141..167 (u16-granular to avoid clobbering col 140)
    #pragma unroll
    for (int r = 0; r < 2; ++r) {
        const int idx = r*256 + t;
        if (idx < 432) {
            const int m = idx/27, c = 141 + (idx - m*27);
            s_q[m*168 + c] = 0;
        }
    }

    // obj_data -> q[.][0..12] (threads 64..79, one object each)
    if (t >= 64 && t < 80) {
        const int o = t - 64, n = ot*16 + o;
        const size_t sb = (size_t)(bi*NN + n)*8;
        const float rd2 = (objects_state[sb+2] - s_mean[2]) / s_std[2];
        const float rd3 = (objects_state[sb+3] - s_mean[3]) / s_std[3];
        const float rd4 = (objects_state[sb+4] - s_mean[4]) / s_std[4];
        const float rd5 = (objects_state[sb+5] - s_mean[5]) / s_std[5];
        const float ca = cosf(rd2), sa = sinf(rd2);
        s_q[o*168 + 0] = (unsigned short)f2bf( ca*rd3 + sa*rd4);
        s_q[o*168 + 1] = (unsigned short)f2bf(-sa*rd3 + ca*rd4);
        s_q[o*168 + 2] = (unsigned short)f2bf(rd5);
        #pragma unroll
        for (int c = 0; c < 10; ++c)
            s_q[o*168 + 3 + c] = (unsigned short)f2bf(
                (objects_shape[(size_t)(bi*NN+n)*10 + c] - sh_mean[c]) / sh_std[c]);
    }

    // ---- W2 GEMM: agg = hsum @ W2 + cnt*b2 -> q[.][13..140] ----
    {
        const uint4* hsrc = (const uint4*)(ws + WSH_OFF);
        U4 af[8];
        #pragma unroll
        for (int kc = 0; kc < 8; ++kc)
            af[kc].u = hsrc[(size_t)(obj0 + col16)*32 + kc*4 + quad];
        float cntv[4];
        #pragma unroll
        for (int i = 0; i < 4; ++i)
            cntv[i] = (float)((const int*)(ws + WSC_OFF))[obj0 + quad*4 + i];
        const uint4* w2f = (const uint4*)(ws + WS2_OFF);
        #pragma unroll
        for (int ntl = 0; ntl < 2; ++ntl) {
            const int nt = wv*2 + ntl, col = nt*16 + col16;
            f32x4 acc = {0.f, 0.f, 0.f, 0.f};
            #pragma unroll
            for (int kc = 0; kc < 8; ++kc) {
                U4 bu; bu.u = w2f[(nt*8 + kc)*64 + lane];
                acc = __builtin_amdgcn_mfma_f32_16x16x32_bf16(af[kc].b, bu.b, acc, 0, 0, 0);
            }
            const float b2v = b2[col];
            #pragma unroll
            for (int i = 0; i < 4; ++i) {
                const int row = quad*4 + i;
                s_q[row*168 + 13 + col] = (unsigned short)f2bf(acc[i] + cntv[i]*b2v);
            }
        }
    }
    __syncthreads();

    // ---- W3 GEMM + relu + W4 partials ----
    {
        U4 af3[5];
        #pragma unroll
        for (int kc = 0; kc < 5; ++kc)
            af3[kc].u = *(const uint4*)&s_q[col16*168 + kc*32 + quad*8];
        const uint4* w3f = (const uint4*)(ws + WS3_OFF);
        float p[4][3];
        #pragma unroll
        for (int i = 0; i < 4; ++i) { p[i][0]=0.f; p[i][1]=0.f; p[i][2]=0.f; }
        #pragma unroll
        for (int ntl = 0; ntl < 4; ++ntl) {
            const int nt = wv*4 + ntl, col = nt*16 + col16;
            f32x4 acc = {0.f, 0.f, 0.f, 0.f};
            #pragma unroll
            for (int kc = 0; kc < 5; ++kc) {
                U4 bu; bu.u = w3f[(nt*5 + kc)*64 + lane];
                acc = __builtin_amdgcn_mfma_f32_16x16x32_bf16(af3[kc].b, bu.b, acc, 0, 0, 0);
            }
            const float b3v = b3[col];
            const float w40 = W4[col*3+0], w41 = W4[col*3+1], w42 = W4[col*3+2];
            #pragma unroll
            for (int i = 0; i < 4; ++i) {
                const float h = fmaxf(acc[i] + b3v, 0.f);
                p[i][0] = fmaf(h, w40, p[i][0]);
                p[i][1] = fmaf(h, w41, p[i][1]);
                p[i][2] = fmaf(h, w42, p[i][2]);
            }
        }
        #pragma unroll
        for (int off = 1; off < 16; off <<= 1)
            #pragma unroll
            for (int i = 0; i < 4; ++i) {
                p[i][0] += __shfl_xor(p[i][0], off);
                p[i][1] += __shfl_xor(p[i][1], off);
                p[i][2] += __shfl_xor(p[i][2], off);
            }
        if (col16 == 0)
            #pragma unroll
            for (int i = 0; i < 4; ++i) {
                s_red[wv][quad*4+i][0] = p[i][0];
                s_red[wv][quad*4+i][1] = p[i][1];
                s_red[wv][quad*4+i][2] = p[i][2];
            }
    }
    __syncthreads();
    if (t < 48) {
        const int m = t/3, o = t - m*3;
        s_outv[m][o] = b4[o] + s_red[0][m][o] + s_red[1][m][o]
                             + s_red[2][m][o] + s_red[3][m][o];
    }
    __syncthreads();

    // ---- epilogue ----
    if (t < 96) {
        const int m = t/6, i = t - m*6, n = ot*16 + m;
        if (n >= 1) {
            const float q0 = s_outv[m][0]*v_std[0] + v_mean[0];
            const float q1 = s_outv[m][1]*v_std[1] + v_mean[1];
            const float q2 = s_outv[m][2]*v_std[2] + v_mean[2];
            const float ang = objects_state[(size_t)(bi*NN+n)*8 + 2];
            const float ca = cosf(ang), sa = sinf(ang);
            const float xd0 = ca*q0 - sa*q1;
            const float xd1 = sa*q0 + ca*q1;
            const int im = i % 3;
            const float xd = (im == 0) ? xd0 : (im == 1) ? xd1 : q2;
            const float base = (i < 3) ? objects_state[(size_t)(bi*NN+n)*8 + i] : 0.f;
            out[((size_t)bi*NM1 + (n-1))*6 + i] = base + xd;
        }
    }
}

extern "C" void kernel_launch(void* const* d_in, const int* in_sizes, int n_in,
                              void* d_out, int out_size, void* d_ws, size_t ws_size,
                              hipStream_t stream) {
    const float* objects_state = (const float*)d_in[0];
    const float* objects_shape = (const float*)d_in[1];
    const float* relation_info = (const float*)d_in[2];
    const float* s_mean  = (const float*)d_in[3];
    const float* s_std   = (const float*)d_in[4];
    const float* sh_mean = (const float*)d_in[5];
    const float* sh_std  = (const float*)d_in[6];
    const float* v_mean  = (const float*)d_in[7];
    const float* v_std   = (const float*)d_in[8];
    const float* W1 = (const float*)d_in[9];
    const float* b1 = (const float*)d_in[10];
    const float* W2 = (const float*)d_in[11];
    const float* b2 = (const float*)d_in[12];
    const float* W3 = (const float*)d_in[13];
    const float* b3 = (const float*)d_in[14];
    const float* W4 = (const float*)d_in[15];
    const float* b4 = (const float*)d_in[16];
    unsigned char* ws = (unsigned char*)d_ws;

    pack_kernel<<<dim3(160), dim3(64), 0, stream>>>(W1, W2, W3, ws);
    rel_kernel<<<dim3(BB*16), dim3(256), 0, stream>>>(
        objects_state, objects_shape, relation_info,
        s_mean, s_std, sh_mean, sh_std, b1, ws);
    obj_kernel<<<dim3(BB*4), dim3(256), 0, stream>>>(
        objects_state, objects_shape,
        s_mean, s_std, sh_mean, sh_std, v_mean, v_std,
        b2, b3, W4, b4, ws, (float*)d_out);
}

// Round 5
// 105.635 us; speedup vs baseline: 5.0937x; 1.0376x over previous
//
#include <hip/hip_runtime.h>
#include <math.h>

#define BB 64
#define NN 64
#define NM1 63
#define RR (NN*(NN-1))

// workspace layout (bytes)
#define WS1_OFF 0              // W1c B-frags: 16 tiles * 64 * 16B = 16 KB
#define WS2_OFF 16384          // W2 B-frags: 8 nt * 8 kc * 64 * 16B = 64 KB
#define WS3_OFF 81920          // W3 B-frags: 16 nt * 5 kc * 64 * 16B = 80 KB
#define WSO_OFF 163840         // per-object prep: 4096 obj * 28 f32 = 459 KB

typedef short bf16x8 __attribute__((ext_vector_type(8)));
typedef float f32x4 __attribute__((ext_vector_type(4)));
union U4 { uint4 u; bf16x8 b; };

__device__ inline unsigned int f2bf(float f) {
    unsigned int u = __float_as_uint(f);
    return (u + 0x7FFFu + ((u >> 16) & 1u)) >> 16;   // RNE fp32->bf16
}
__device__ inline unsigned int pack2(float a, float b) {
    return f2bf(a) | (f2bf(b) << 16);
}

// ============ prep: weight pack (blocks 0..39) + object precompute (40..55) =
// Per-object record (28 f32): [0]=st0 [1]=st1 [2..9]=nst [10..19]=nsh
// [20]=cos(nst2) [21]=sin(nst2) [22]=cos(st2) [23]=sin(st2)
// [24]=vrot0 [25]=vrot1 [26]=st2raw [27]=pad
__global__ __launch_bounds__(256) void prep_kernel(
    const float* __restrict__ objects_state,
    const float* __restrict__ objects_shape,
    const float* __restrict__ s_mean, const float* __restrict__ s_std,
    const float* __restrict__ sh_mean, const float* __restrict__ sh_std,
    const float* __restrict__ W1, const float* __restrict__ W2,
    const float* __restrict__ W3, unsigned char* __restrict__ ws)
{
    const int t = threadIdx.x;
    if (blockIdx.x < 40) {
        const int u = blockIdx.x*4 + (t >> 6), l = t & 63;
        const int col16 = l & 15, quad = l >> 4;
        float v[8];
        uint4* dst;
        if (u < 16) {
            const int nt = u, col = nt*16 + col16;
            #pragma unroll
            for (int j = 0; j < 8; ++j) {
                const int k = quad*8 + j;
                const int orig = k < 12 ? k : (k < 22 ? k+10 : k-10);
                v[j] = W1[orig*256 + col];
            }
            dst = (uint4*)(ws + WS1_OFF) + (nt*64 + l);
        } else if (u < 80) {
            const int w = u-16, nt = w >> 3, kc = w & 7, col = nt*16 + col16;
            #pragma unroll
            for (int j = 0; j < 8; ++j)
                v[j] = W2[(size_t)(kc*32 + quad*8 + j)*128 + col];
            dst = (uint4*)(ws + WS2_OFF) + ((nt*8 + kc)*64 + l);
        } else {
            const int w = u-80, nt = w/5, kc = w - nt*5, col = nt*16 + col16;
            #pragma unroll
            for (int j = 0; j < 8; ++j) {
                const int k = kc*32 + quad*8 + j;
                v[j] = (k < 141) ? W3[(size_t)k*256 + col] : 0.f;
            }
            dst = (uint4*)(ws + WS3_OFF) + ((nt*5 + kc)*64 + l);
        }
        uint4 o;
        o.x = pack2(v[0], v[1]); o.y = pack2(v[2], v[3]);
        o.z = pack2(v[4], v[5]); o.w = pack2(v[6], v[7]);
        *dst = o;
    } else {
        const int obj = (blockIdx.x - 40)*256 + t;
        float st[8], sh[10];
        #pragma unroll
        for (int c = 0; c < 8; ++c)  st[c] = objects_state[(size_t)obj*8 + c];
        #pragma unroll
        for (int c = 0; c < 10; ++c) sh[c] = objects_shape[(size_t)obj*10 + c];
        float f[28];
        f[0] = st[0]; f[1] = st[1]; f[26] = st[2]; f[27] = 0.f;
        #pragma unroll
        for (int c = 0; c < 8; ++c)  f[2+c]  = (st[c] - s_mean[c]) / s_std[c];
        #pragma unroll
        for (int c = 0; c < 10; ++c) f[10+c] = (sh[c] - sh_mean[c]) / sh_std[c];
        float sa, ca, sr, cr;
        __sincosf(f[4], &sa, &ca);       // nst2
        __sincosf(st[2], &sr, &cr);      // raw angle
        // match reference precision closely: use sinf/cosf (libm) instead if
        // fast-math versions drift; threshold is generous so fast is fine
        sa = sinf(f[4]); ca = cosf(f[4]);
        sr = sinf(st[2]); cr = cosf(st[2]);
        f[20] = ca; f[21] = sa; f[22] = cr; f[23] = sr;
        f[24] =  ca*f[5] + sa*f[6];
        f[25] = -sa*f[5] + ca*f[6];
        float4* dst = (float4*)(ws + WSO_OFF + (size_t)obj*112);
        #pragma unroll
        for (int q = 0; q < 7; ++q)
            dst[q] = make_float4(f[q*4], f[q*4+1], f[q*4+2], f[q*4+3]);
    }
}

// ============ main: G=8 receivers/block, 512 threads, grid B*8 ============
// Fused: relation build -> MLP1 MFMA -> W2 MFMA -> W3 MFMA -> W4 -> epilogue.
// MLP1: zero-padded rows + post-hoc pad*relu(b1) correction (no per-row mask).
__global__ __launch_bounds__(512) void main_kernel(
    const float* __restrict__ relation_info,
    const float* __restrict__ v_mean, const float* __restrict__ v_std,
    const float* __restrict__ b1, const float* __restrict__ b2,
    const float* __restrict__ b3,
    const float* __restrict__ W4, const float* __restrict__ b4,
    const unsigned char* __restrict__ ws,
    float* __restrict__ out)
{
    __shared__ __align__(16) float P[64][28];                 // 7168 B
    __shared__ __align__(16) unsigned int relb_w[8*64*16];    // 32768 B (row=64B)
    __shared__ __align__(16) float RI[1512];                  // 6048 B
    __shared__ __align__(16) unsigned short s_h[16*264];      // 8448 B
    __shared__ __align__(16) unsigned short s_q[16*168];      // 5376 B
    __shared__ int   s_cntg[8];
    __shared__ float s_red[8][16][3];
    __shared__ float s_outv[16][3];

    const int b  = blockIdx.x >> 3;
    const int nb = (blockIdx.x & 7) * 8;
    const int t  = threadIdx.x;
    const int wv = t >> 6, lane = t & 63, col16 = lane & 15, quad = lane >> 4;

    // ---- Phase 0: stage ----
    {
        uint4 z = make_uint4(0,0,0,0);
        uint4* relb4 = (uint4*)relb_w;
        #pragma unroll
        for (int r = 0; r < 4; ++r) relb4[r*512 + t] = z;
        if (t < 336) ((uint4*)s_q)[t] = z;
        if (t < 8) s_cntg[t] = 0;
        const float* psrc = (const float*)(ws + WSO_OFF + (size_t)(b*64)*112);
        float* P0 = &P[0][0];
        #pragma unroll
        for (int r = 0; r < 4; ++r) {
            const int idx = r*512 + t;
            if (idx < 1792) P0[idx] = psrc[idx];
        }
        const float* rsrc = relation_info + ((size_t)b*RR + nb*NM1)*3;
        #pragma unroll
        for (int r = 0; r < 3; ++r) {
            const int idx = r*512 + t;
            if (idx < 1512) RI[idx] = rsrc[idx];
        }
    }
    __syncthreads();

    // ---- Phase 1: build relation rows (1 candidate/thread) ----
    if (t < 504) {
        const int g = t/63, k = t - g*63, n = nb + g, j = k + (k >= n);
        const float dx = P[n][0] - P[j][0];
        const float dy = P[n][1] - P[j][1];
        const float dist = sqrtf(dx*dx + dy*dy);
        if (dist < 0.35f && dist != 0.0f) {
            const int slot = atomicAdd(&s_cntg[g], 1);
            const int row = (g << 6) + slot;
            float f[32];
            f[0] = RI[t*3]; f[1] = RI[t*3+1]; f[2] = RI[t*3+2];
            const float rd0 = P[n][2], rd1 = P[n][3], rd2 = P[n][4],
                        rd3 = P[n][5], rd4 = P[n][6], rd5 = P[n][7];
            const float ca = P[n][20], sa = P[n][21];
            const float d0 = P[j][2]-rd0, d1 = P[j][3]-rd1, d2 = P[j][4]-rd2,
                        d3 = P[j][5]-rd3, d4 = P[j][6]-rd4, d5 = P[j][7]-rd5;
            f[3]  =  ca*d0 + sa*d1;
            f[4]  = -sa*d0 + ca*d1;
            f[5]  =  ca*d3 + sa*d4;
            f[6]  = -sa*d3 + ca*d4;
            f[7]  =  ca*P[j][8] + sa*P[j][9];
            f[8]  = -sa*P[j][8] + ca*P[j][9];
            f[9]  = sinf(2.f*d2);
            f[10] = cosf(2.f*d2);
            f[11] = d5;
            #pragma unroll
            for (int c = 0; c < 10; ++c) f[12+c] = P[j][10+c];   // sender shape
            #pragma unroll
            for (int c = 0; c < 10; ++c) f[22+c] = P[n][10+c];   // receiver shape
            uint4* dst = (uint4*)&relb_w[row*16];
            #pragma unroll
            for (int w4 = 0; w4 < 4; ++w4) {
                uint4 o;
                o.x = pack2(f[w4*8+0], f[w4*8+1]);
                o.y = pack2(f[w4*8+2], f[w4*8+3]);
                o.z = pack2(f[w4*8+4], f[w4*8+5]);
                o.w = pack2(f[w4*8+6], f[w4*8+7]);
                dst[w4] = o;
            }
        }
    }
    __syncthreads();

    // ---- Phase 2: MLP1 MFMA (per wave: 2 N-tiles) ----
    {
        int cg[8];
        #pragma unroll
        for (int g = 0; g < 8; ++g) cg[g] = s_cntg[g];
        const uint4* w1f = (const uint4*)(ws + WS1_OFF);
        U4 bu0, bu1;
        bu0.u = w1f[(wv*2+0)*64 + lane];
        bu1.u = w1f[(wv*2+1)*64 + lane];
        const float b10 = b1[(wv*2+0)*16 + col16];
        const float b11 = b1[(wv*2+1)*16 + col16];
        float hs0[8], hs1[8];
        #pragma unroll
        for (int g = 0; g < 8; ++g) { hs0[g] = 0.f; hs1[g] = 0.f; }
        #pragma unroll
        for (int g = 0; g < 8; ++g) {
            const int mts = (cg[g] + 15) >> 4;
            for (int mt = 0; mt < mts; ++mt) {
                U4 au;
                au.u = *(const uint4*)&relb_w[((g<<6) + mt*16 + col16)*16 + quad*4];
                f32x4 a0 = {0.f,0.f,0.f,0.f}, a1 = {0.f,0.f,0.f,0.f};
                a0 = __builtin_amdgcn_mfma_f32_16x16x32_bf16(au.b, bu0.b, a0, 0,0,0);
                a1 = __builtin_amdgcn_mfma_f32_16x16x32_bf16(au.b, bu1.b, a1, 0,0,0);
                #pragma unroll
                for (int i = 0; i < 4; ++i) {
                    hs0[g] += fmaxf(a0[i] + b10, 0.f);
                    hs1[g] += fmaxf(a1[i] + b11, 0.f);
                }
            }
        }
        const float rb0 = fmaxf(b10, 0.f), rb1 = fmaxf(b11, 0.f);
        #pragma unroll
        for (int g = 0; g < 8; ++g) {
            const int mts = (cg[g] + 15) >> 4;
            const float pad = (float)(mts*16 - cg[g]);
            float v0 = hs0[g], v1 = hs1[g];
            v0 += __shfl_xor(v0, 16); v0 += __shfl_xor(v0, 32);
            v1 += __shfl_xor(v1, 16); v1 += __shfl_xor(v1, 32);
            if (quad == 0) {
                s_h[g*264 + (wv*2+0)*16 + col16] =
                    (unsigned short)f2bf(v0 - pad*rb0);
                s_h[g*264 + (wv*2+1)*16 + col16] =
                    (unsigned short)f2bf(v1 - pad*rb1);
            }
        }
    }
    __syncthreads();

    // ---- Phase 3: obj_data q[0..12] + W2 GEMM -> q[13..140] ----
    if (t < 104) {
        const int m = t/13, c = t - m*13, n = nb + m;
        float v;
        if (c == 0) v = P[n][24];
        else if (c == 1) v = P[n][25];
        else if (c == 2) v = P[n][7];
        else v = P[n][10 + c - 3];
        s_q[m*168 + c] = (unsigned short)f2bf(v);
    }
    {
        U4 af[8];
        #pragma unroll
        for (int kc = 0; kc < 8; ++kc)
            af[kc].u = *(const uint4*)&s_h[(lane & 15)*264 + kc*32 + quad*8];
        float cntv[4];
        #pragma unroll
        for (int i = 0; i < 4; ++i)
            cntv[i] = (float)s_cntg[(quad*4 + i) & 7];
        const uint4* w2f = (const uint4*)(ws + WS2_OFF);
        f32x4 acc = {0.f,0.f,0.f,0.f};
        #pragma unroll
        for (int kc = 0; kc < 8; ++kc) {
            U4 bu; bu.u = w2f[(wv*8 + kc)*64 + lane];
            acc = __builtin_amdgcn_mfma_f32_16x16x32_bf16(af[kc].b, bu.b, acc, 0,0,0);
        }
        const float b2v = b2[wv*16 + col16];
        #pragma unroll
        for (int i = 0; i < 4; ++i) {
            const int row = quad*4 + i;
            s_q[row*168 + 13 + wv*16 + col16] =
                (unsigned short)f2bf(acc[i] + cntv[i]*b2v);
        }
    }
    __syncthreads();

    // ---- Phase 4: W3 GEMM + relu + W4 partials ----
    {
        U4 af3[5];
        #pragma unroll
        for (int kc = 0; kc < 5; ++kc)
            af3[kc].u = *(const uint4*)&s_q[(lane & 15)*168 + kc*32 + quad*8];
        const uint4* w3f = (const uint4*)(ws + WS3_OFF);
        float p[4][3];
        #pragma unroll
        for (int i = 0; i < 4; ++i) { p[i][0]=0.f; p[i][1]=0.f; p[i][2]=0.f; }
        #pragma unroll
        for (int ntl = 0; ntl < 2; ++ntl) {
            const int nt = wv + ntl*8, col = nt*16 + col16;
            f32x4 acc = {0.f,0.f,0.f,0.f};
            #pragma unroll
            for (int kc = 0; kc < 5; ++kc) {
                U4 bu; bu.u = w3f[(nt*5 + kc)*64 + lane];
                acc = __builtin_amdgcn_mfma_f32_16x16x32_bf16(af3[kc].b, bu.b, acc, 0,0,0);
            }
            const float b3v = b3[col];
            const float w40 = W4[col*3+0], w41 = W4[col*3+1], w42 = W4[col*3+2];
            #pragma unroll
            for (int i = 0; i < 4; ++i) {
                const float h = fmaxf(acc[i] + b3v, 0.f);
                p[i][0] = fmaf(h, w40, p[i][0]);
                p[i][1] = fmaf(h, w41, p[i][1]);
                p[i][2] = fmaf(h, w42, p[i][2]);
            }
        }
        #pragma unroll
        for (int off = 1; off < 16; off <<= 1)
            #pragma unroll
            for (int i = 0; i < 4; ++i) {
                p[i][0] += __shfl_xor(p[i][0], off);
                p[i][1] += __shfl_xor(p[i][1], off);
                p[i][2] += __shfl_xor(p[i][2], off);
            }
        if (col16 == 0)
            #pragma unroll
            for (int i = 0; i < 4; ++i) {
                s_red[wv][quad*4+i][0] = p[i][0];
                s_red[wv][quad*4+i][1] = p[i][1];
                s_red[wv][quad*4+i][2] = p[i][2];
            }
    }
    __syncthreads();
    if (t < 48) {
        const int m = t/3, o = t - m*3;
        float acc = b4[o];
        #pragma unroll
        for (int w = 0; w < 8; ++w) acc += s_red[w][m][o];
        s_outv[m][o] = acc;
    }
    __syncthreads();

    // ---- Phase 5: epilogue ----
    if (t < 48) {
        const int m = t/6, i = t - m*6, n = nb + m;
        if (n >= 1) {
            const float q0 = s_outv[m][0]*v_std[0] + v_mean[0];
            const float q1 = s_outv[m][1]*v_std[1] + v_mean[1];
            const float q2 = s_outv[m][2]*v_std[2] + v_mean[2];
            const float cr = P[n][22], sr = P[n][23];
            const float xd0 = cr*q0 - sr*q1;
            const float xd1 = sr*q0 + cr*q1;
            const int im = i % 3;
            const float xd = (im == 0) ? xd0 : (im == 1) ? xd1 : q2;
            float base = 0.f;
            if (i == 0) base = P[n][0];
            else if (i == 1) base = P[n][1];
            else if (i == 2) base = P[n][26];
            out[((size_t)b*NM1 + (n-1))*6 + i] = base + xd;
        }
    }
}

extern "C" void kernel_launch(void* const* d_in, const int* in_sizes, int n_in,
                              void* d_out, int out_size, void* d_ws, size_t ws_size,
                              hipStream_t stream) {
    const float* objects_state = (const float*)d_in[0];
    const float* objects_shape = (const float*)d_in[1];
    const float* relation_info = (const float*)d_in[2];
    const float* s_mean  = (const float*)d_in[3];
    const float* s_std   = (const float*)d_in[4];
    const float* sh_mean = (const float*)d_in[5];
    const float* sh_std  = (const float*)d_in[6];
    const float* v_mean  = (const float*)d_in[7];
    const float* v_std   = (const float*)d_in[8];
    const float* W1 = (const float*)d_in[9];
    const float* b1 = (const float*)d_in[10];
    const float* W2 = (const float*)d_in[11];
    const float* b2 = (const float*)d_in[12];
    const float* W3 = (const float*)d_in[13];
    const float* b3 = (const float*)d_in[14];
    const float* W4 = (const float*)d_in[15];
    const float* b4 = (const float*)d_in[16];
    unsigned char* ws = (unsigned char*)d_ws;

    prep_kernel<<<dim3(56), dim3(256), 0, stream>>>(
        objects_state, objects_shape, s_mean, s_std, sh_mean, sh_std,
        W1, W2, W3, ws);
    main_kernel<<<dim3(BB*8), dim3(512), 0, stream>>>(
        relation_info, v_mean, v_std, b1, b2, b3, W4, b4,
        ws, (float*)d_out);
}

// Round 8
// 105.601 us; speedup vs baseline: 5.0953x; 1.0003x over previous
//
#include <hip/hip_runtime.h>
#include <math.h>

#define BB 64
#define NN 64
#define NM1 63
#define RR (NN*(NN-1))

// workspace layout (bytes)
#define WS1_OFF 0              // W1c B-frags: 16 tiles * 64 * 16B = 16 KB
#define WS2_OFF 16384          // W2 B-frags: 8 nt * 8 kc * 64 * 16B = 64 KB
#define WS3_OFF 81920          // W3 B-frags: 16 nt * 5 kc * 64 * 16B = 80 KB
#define WSO_OFF 163840         // per-object prep: 4096 obj * 28 f32 = 459 KB

typedef short bf16x8 __attribute__((ext_vector_type(8)));
typedef float f32x4 __attribute__((ext_vector_type(4)));
union U4 { uint4 u; bf16x8 b; };

__device__ inline unsigned int f2bf(float f) {
    unsigned int u = __float_as_uint(f);
    return (u + 0x7FFFu + ((u >> 16) & 1u)) >> 16;   // RNE fp32->bf16
}
__device__ inline unsigned int pack2(float a, float b) {
    return f2bf(a) | (f2bf(b) << 16);
}

// ============ prep: weight pack (blocks 0..39) + object precompute (40..55) =
// Per-object record (28 f32): [0]=st0 [1]=st1 [2..9]=nst [10..19]=nsh
// [20]=cos(nst2) [21]=sin(nst2) [22]=cos(st2) [23]=sin(st2)
// [24]=vrot0 [25]=vrot1 [26]=st2raw [27]=pad
__global__ __launch_bounds__(256) void prep_kernel(
    const float* __restrict__ objects_state,
    const float* __restrict__ objects_shape,
    const float* __restrict__ s_mean, const float* __restrict__ s_std,
    const float* __restrict__ sh_mean, const float* __restrict__ sh_std,
    const float* __restrict__ W1, const float* __restrict__ W2,
    const float* __restrict__ W3, unsigned char* __restrict__ ws)
{
    const int t = threadIdx.x;
    if (blockIdx.x < 40) {
        const int u = blockIdx.x*4 + (t >> 6), l = t & 63;
        const int col16 = l & 15, quad = l >> 4;
        float v[8];
        uint4* dst;
        if (u < 16) {
            // W1 compact rows: kc<12 -> orig kc; 12..21 -> orig kc+10 (sender
            // shape); 22..31 -> orig kc-10 (receiver shape)
            const int nt = u, col = nt*16 + col16;
            #pragma unroll
            for (int j = 0; j < 8; ++j) {
                const int k = quad*8 + j;
                const int orig = k < 12 ? k : (k < 22 ? k+10 : k-10);
                v[j] = W1[orig*256 + col];
            }
            dst = (uint4*)(ws + WS1_OFF) + (nt*64 + l);
        } else if (u < 80) {
            const int w = u-16, nt = w >> 3, kc = w & 7, col = nt*16 + col16;
            #pragma unroll
            for (int j = 0; j < 8; ++j)
                v[j] = W2[(size_t)(kc*32 + quad*8 + j)*128 + col];
            dst = (uint4*)(ws + WS2_OFF) + ((nt*8 + kc)*64 + l);
        } else {
            const int w = u-80, nt = w/5, kc = w - nt*5, col = nt*16 + col16;
            #pragma unroll
            for (int j = 0; j < 8; ++j) {
                const int k = kc*32 + quad*8 + j;
                v[j] = (k < 141) ? W3[(size_t)k*256 + col] : 0.f;  // zero K-pad:
                // lets consumers skip A-side K-pad zeroing entirely
            }
            dst = (uint4*)(ws + WS3_OFF) + ((nt*5 + kc)*64 + l);
        }
        uint4 o;
        o.x = pack2(v[0], v[1]); o.y = pack2(v[2], v[3]);
        o.z = pack2(v[4], v[5]); o.w = pack2(v[6], v[7]);
        *dst = o;
    } else {
        const int obj = (blockIdx.x - 40)*256 + t;
        float st[8], sh[10];
        #pragma unroll
        for (int c = 0; c < 8; ++c)  st[c] = objects_state[(size_t)obj*8 + c];
        #pragma unroll
        for (int c = 0; c < 10; ++c) sh[c] = objects_shape[(size_t)obj*10 + c];
        float f[28];
        f[0] = st[0]; f[1] = st[1]; f[26] = st[2]; f[27] = 0.f;
        #pragma unroll
        for (int c = 0; c < 8; ++c)  f[2+c]  = (st[c] - s_mean[c]) / s_std[c];
        #pragma unroll
        for (int c = 0; c < 10; ++c) f[10+c] = (sh[c] - sh_mean[c]) / sh_std[c];
        float sa, ca, sr, cr;
        __sincosf(f[4], &sa, &ca);       // nst2
        __sincosf(st[2], &sr, &cr);      // raw angle
        // match reference precision closely: use sinf/cosf (libm) instead if
        // fast-math versions drift; threshold is generous so fast is fine
        sa = sinf(f[4]); ca = cosf(f[4]);
        sr = sinf(st[2]); cr = cosf(st[2]);
        f[20] = ca; f[21] = sa; f[22] = cr; f[23] = sr;
        f[24] =  ca*f[5] + sa*f[6];
        f[25] = -sa*f[5] + ca*f[6];
        float4* dst = (float4*)(ws + WSO_OFF + (size_t)obj*112);
        #pragma unroll
        for (int q = 0; q < 7; ++q)
            dst[q] = make_float4(f[q*4], f[q*4+1], f[q*4+2], f[q*4+3]);
    }
}

// ============ main: G=8 receivers/block, 512 threads, grid B*8 ============
// Fused: relation build -> MLP1 MFMA -> W2 MFMA -> W3 MFMA -> W4 -> epilogue.
// MLP1: zero-padded rows + post-hoc pad*relu(b1) correction (no per-row mask).
__global__ __launch_bounds__(512) void main_kernel(
    const float* __restrict__ relation_info,
    const float* __restrict__ v_mean, const float* __restrict__ v_std,
    const float* __restrict__ b1, const float* __restrict__ b2,
    const float* __restrict__ b3,
    const float* __restrict__ W4, const float* __restrict__ b4,
    const unsigned char* __restrict__ ws,
    float* __restrict__ out)
{
    __shared__ __align__(16) float P[64][28];                 // 7168 B
    __shared__ __align__(16) unsigned int relb_w[8*64*16];    // 32768 B (row=64B)
    __shared__ __align__(16) float RI[1512];                  // 6048 B
    __shared__ __align__(16) unsigned short s_h[16*264];      // 8448 B
    __shared__ __align__(16) unsigned short s_q[16*168];      // 5376 B
    __shared__ int   s_cntg[8];
    __shared__ float s_red[8][16][3];
    __shared__ float s_outv[16][3];

    const int b  = blockIdx.x >> 3;
    const int nb = (blockIdx.x & 7) * 8;
    const int t  = threadIdx.x;
    const int wv = t >> 6, lane = t & 63, col16 = lane & 15, quad = lane >> 4;

    // ---- Phase 0: stage ----
    {
        uint4 z = make_uint4(0,0,0,0);
        uint4* relb4 = (uint4*)relb_w;
        #pragma unroll
        for (int r = 0; r < 4; ++r) relb4[r*512 + t] = z;
        if (t < 336) ((uint4*)s_q)[t] = z;
        if (t < 8) s_cntg[t] = 0;
        const float* psrc = (const float*)(ws + WSO_OFF + (size_t)(b*64)*112);
        float* P0 = &P[0][0];
        #pragma unroll
        for (int r = 0; r < 4; ++r) {
            const int idx = r*512 + t;
            if (idx < 1792) P0[idx] = psrc[idx];
        }
        const float* rsrc = relation_info + ((size_t)b*RR + nb*NM1)*3;
        #pragma unroll
        for (int r = 0; r < 3; ++r) {
            const int idx = r*512 + t;
            if (idx < 1512) RI[idx] = rsrc[idx];
        }
    }
    __syncthreads();

    // ---- Phase 1: build relation rows (1 candidate/thread) ----
    if (t < 504) {
        const int g = t/63, k = t - g*63, n = nb + g, j = k + (k >= n);
        const float dx = P[n][0] - P[j][0];
        const float dy = P[n][1] - P[j][1];
        const float dist = sqrtf(dx*dx + dy*dy);
        if (dist < 0.35f && dist != 0.0f) {
            const int slot = atomicAdd(&s_cntg[g], 1);
            const int row = (g << 6) + slot;
            float f[32];
            f[0] = RI[t*3]; f[1] = RI[t*3+1]; f[2] = RI[t*3+2];
            const float rd0 = P[n][2], rd1 = P[n][3], rd2 = P[n][4],
                        rd3 = P[n][5], rd4 = P[n][6], rd5 = P[n][7];
            const float ca = P[n][20], sa = P[n][21];
            const float d0 = P[j][2]-rd0, d1 = P[j][3]-rd1, d2 = P[j][4]-rd2,
                        d3 = P[j][5]-rd3, d4 = P[j][6]-rd4, d5 = P[j][7]-rd5;
            f[3]  =  ca*d0 + sa*d1;
            f[4]  = -sa*d0 + ca*d1;
            f[5]  =  ca*d3 + sa*d4;
            f[6]  = -sa*d3 + ca*d4;
            f[7]  =  ca*P[j][8] + sa*P[j][9];
            f[8]  = -sa*P[j][8] + ca*P[j][9];
            f[9]  = sinf(2.f*d2);
            f[10] = cosf(2.f*d2);
            f[11] = d5;
            #pragma unroll
            for (int c = 0; c < 10; ++c) f[12+c] = P[j][10+c];   // sender shape
            #pragma unroll
            for (int c = 0; c < 10; ++c) f[22+c] = P[n][10+c];   // receiver shape
            uint4* dst = (uint4*)&relb_w[row*16];
            #pragma unroll
            for (int w4 = 0; w4 < 4; ++w4) {
                uint4 o;
                o.x = pack2(f[w4*8+0], f[w4*8+1]);
                o.y = pack2(f[w4*8+2], f[w4*8+3]);
                o.z = pack2(f[w4*8+4], f[w4*8+5]);
                o.w = pack2(f[w4*8+6], f[w4*8+7]);
                dst[w4] = o;
            }
        }
    }
    __syncthreads();

    // ---- Phase 2: MLP1 MFMA (per wave: 2 N-tiles over 8 groups) ----
    {
        int cg[8];
        #pragma unroll
        for (int g = 0; g < 8; ++g) cg[g] = s_cntg[g];
        const uint4* w1f = (const uint4*)(ws + WS1_OFF);
        U4 bu0, bu1;
        bu0.u = w1f[(wv*2+0)*64 + lane];
        bu1.u = w1f[(wv*2+1)*64 + lane];
        const float b10 = b1[(wv*2+0)*16 + col16];
        const float b11 = b1[(wv*2+1)*16 + col16];
        float hs0[8], hs1[8];
        #pragma unroll
        for (int g = 0; g < 8; ++g) { hs0[g] = 0.f; hs1[g] = 0.f; }
        #pragma unroll
        for (int g = 0; g < 8; ++g) {
            const int mts = (cg[g] + 15) >> 4;
            for (int mt = 0; mt < mts; ++mt) {
                U4 au;
                au.u = *(const uint4*)&relb_w[((g<<6) + mt*16 + col16)*16 + quad*4];
                f32x4 a0 = {0.f,0.f,0.f,0.f}, a1 = {0.f,0.f,0.f,0.f};
                a0 = __builtin_amdgcn_mfma_f32_16x16x32_bf16(au.b, bu0.b, a0, 0,0,0);
                a1 = __builtin_amdgcn_mfma_f32_16x16x32_bf16(au.b, bu1.b, a1, 0,0,0);
                #pragma unroll
                for (int i = 0; i < 4; ++i) {
                    hs0[g] += fmaxf(a0[i] + b10, 0.f);
                    hs1[g] += fmaxf(a1[i] + b11, 0.f);
                }
            }
        }
        // zero pad rows each contributed relu(b1); subtract them post-hoc
        const float rb0 = fmaxf(b10, 0.f), rb1 = fmaxf(b11, 0.f);
        #pragma unroll
        for (int g = 0; g < 8; ++g) {
            const int mts = (cg[g] + 15) >> 4;
            const float pad = (float)(mts*16 - cg[g]);
            float v0 = hs0[g], v1 = hs1[g];
            v0 += __shfl_xor(v0, 16); v0 += __shfl_xor(v0, 32);
            v1 += __shfl_xor(v1, 16); v1 += __shfl_xor(v1, 32);
            if (quad == 0) {
                s_h[g*264 + (wv*2+0)*16 + col16] =
                    (unsigned short)f2bf(v0 - pad*rb0);
                s_h[g*264 + (wv*2+1)*16 + col16] =
                    (unsigned short)f2bf(v1 - pad*rb1);
            }
        }
    }
    __syncthreads();

    // ---- Phase 3: obj_data q[0..12] + W2 GEMM -> q[13..140] ----
    if (t < 104) {
        const int m = t/13, c = t - m*13, n = nb + m;
        float v;
        if (c == 0) v = P[n][24];
        else if (c == 1) v = P[n][25];
        else if (c == 2) v = P[n][7];
        else v = P[n][10 + c - 3];
        s_q[m*168 + c] = (unsigned short)f2bf(v);
    }
    {
        U4 af[8];
        #pragma unroll
        for (int kc = 0; kc < 8; ++kc)
            af[kc].u = *(const uint4*)&s_h[(lane & 15)*264 + kc*32 + quad*8];
        float cntv[4];
        #pragma unroll
        for (int i = 0; i < 4; ++i)
            cntv[i] = (float)s_cntg[(quad*4 + i) & 7];
        const uint4* w2f = (const uint4*)(ws + WS2_OFF);
        f32x4 acc = {0.f,0.f,0.f,0.f};
        #pragma unroll
        for (int kc = 0; kc < 8; ++kc) {
            U4 bu; bu.u = w2f[(wv*8 + kc)*64 + lane];
            acc = __builtin_amdgcn_mfma_f32_16x16x32_bf16(af[kc].b, bu.b, acc, 0,0,0);
        }
        const float b2v = b2[wv*16 + col16];
        #pragma unroll
        for (int i = 0; i < 4; ++i) {
            const int row = quad*4 + i;
            s_q[row*168 + 13 + wv*16 + col16] =
                (unsigned short)f2bf(acc[i] + cntv[i]*b2v);
        }
    }
    __syncthreads();

    // ---- Phase 4: W3 GEMM + relu + W4 partials ----
    {
        U4 af3[5];
        #pragma unroll
        for (int kc = 0; kc < 5; ++kc)
            af3[kc].u = *(const uint4*)&s_q[(lane & 15)*168 + kc*32 + quad*8];
        const uint4* w3f = (const uint4*)(ws + WS3_OFF);
        float p[4][3];
        #pragma unroll
        for (int i = 0; i < 4; ++i) { p[i][0]=0.f; p[i][1]=0.f; p[i][2]=0.f; }
        #pragma unroll
        for (int ntl = 0; ntl < 2; ++ntl) {
            const int nt = wv + ntl*8, col = nt*16 + col16;
            f32x4 acc = {0.f,0.f,0.f,0.f};
            #pragma unroll
            for (int kc = 0; kc < 5; ++kc) {
                U4 bu; bu.u = w3f[(nt*5 + kc)*64 + lane];
                acc = __builtin_amdgcn_mfma_f32_16x16x32_bf16(af3[kc].b, bu.b, acc, 0,0,0);
            }
            const float b3v = b3[col];
            const float w40 = W4[col*3+0], w41 = W4[col*3+1], w42 = W4[col*3+2];
            #pragma unroll
            for (int i = 0; i < 4; ++i) {
                const float h = fmaxf(acc[i] + b3v, 0.f);
                p[i][0] = fmaf(h, w40, p[i][0]);
                p[i][1] = fmaf(h, w41, p[i][1]);
                p[i][2] = fmaf(h, w42, p[i][2]);
            }
        }
        #pragma unroll
        for (int off = 1; off < 16; off <<= 1)
            #pragma unroll
            for (int i = 0; i < 4; ++i) {
                p[i][0] += __shfl_xor(p[i][0], off);
                p[i][1] += __shfl_xor(p[i][1], off);
                p[i][2] += __shfl_xor(p[i][2], off);
            }
        if (col16 == 0)
            #pragma unroll
            for (int i = 0; i < 4; ++i) {
                s_red[wv][quad*4+i][0] = p[i][0];
                s_red[wv][quad*4+i][1] = p[i][1];
                s_red[wv][quad*4+i][2] = p[i][2];
            }
    }
    __syncthreads();
    if (t < 48) {
        const int m = t/3, o = t - m*3;
        float acc = b4[o];
        #pragma unroll
        for (int w = 0; w < 8; ++w) acc += s_red[w][m][o];
        s_outv[m][o] = acc;
    }
    __syncthreads();

    // ---- Phase 5: epilogue ----
    if (t < 48) {
        const int m = t/6, i = t - m*6, n = nb + m;
        if (n >= 1) {
            const float q0 = s_outv[m][0]*v_std[0] + v_mean[0];
            const float q1 = s_outv[m][1]*v_std[1] + v_mean[1];
            const float q2 = s_outv[m][2]*v_std[2] + v_mean[2];
            const float cr = P[n][22], sr = P[n][23];
            const float xd0 = cr*q0 - sr*q1;
            const float xd1 = sr*q0 + cr*q1;
            const int im = i % 3;
            const float xd = (im == 0) ? xd0 : (im == 1) ? xd1 : q2;
            float base = 0.f;
            if (i == 0) base = P[n][0];
            else if (i == 1) base = P[n][1];
            else if (i == 2) base = P[n][26];
            out[((size_t)b*NM1 + (n-1))*6 + i] = base + xd;
        }
    }
}

extern "C" void kernel_launch(void* const* d_in, const int* in_sizes, int n_in,
                              void* d_out, int out_size, void* d_ws, size_t ws_size,
                              hipStream_t stream) {
    const float* objects_state = (const float*)d_in[0];
    const float* objects_shape = (const float*)d_in[1];
    const float* relation_info = (const float*)d_in[2];
    const float* s_mean  = (const float*)d_in[3];
    const float* s_std   = (const float*)d_in[4];
    const float* sh_mean = (const float*)d_in[5];
    const float* sh_std  = (const float*)d_in[6];
    const float* v_mean  = (const float*)d_in[7];
    const float* v_std   = (const float*)d_in[8];
    const float* W1 = (const float*)d_in[9];
    const float* b1 = (const float*)d_in[10];
    const float* W2 = (const float*)d_in[11];
    const float* b2 = (const float*)d_in[12];
    const float* W3 = (const float*)d_in[13];
    const float* b3 = (const float*)d_in[14];
    const float* W4 = (const float*)d_in[15];
    const float* b4 = (const float*)d_in[16];
    unsigned char* ws = (unsigned char*)d_ws;

    prep_kernel<<<dim3(56), dim3(256), 0, stream>>>(
        objects_state, objects_shape, s_mean, s_std, sh_mean, sh_std,
        W1, W2, W3, ws);
    main_kernel<<<dim3(BB*8), dim3(512), 0, stream>>>(
        relation_info, v_mean, v_std, b1, b2, b3, W4, b4,
        ws, (float*)d_out);
}